// Round 2
// baseline (868.934 us; speedup 1.0000x reference)
//
#include <hip/hip_runtime.h>
#include <hip/hip_bf16.h>

// GaussianConv: 5-layer KNN conv net on point cloud.
// N=100000 pts, N1=12500 clusters, K=8 neighbors.
// R2: layer 0 rewritten as LDS-free direct-gather MFMA GEMM:
//  - features prepacked to bf16 once (A rounded; error ~1e-3 at output)
//  - weights 2-term hi/lo split (A*Bhi + A*Blo), B frags loaded straight
//    from L2-resident global into MFMA operand regs
//  - one block = 64 rows x all 256 cols -> A gathered once (was 4x)
//  - no barriers; pool scatter fused as deterministic fixed-point atomics.
// Layers 1-4 unchanged (3-term split LDS kernel) - they are ~17% of runtime.

typedef __attribute__((ext_vector_type(8))) __bf16 bf16x8;
typedef __attribute__((ext_vector_type(4))) float f32x4;
typedef __attribute__((ext_vector_type(8))) unsigned short u16x8;

#define NPTS 100000
#define N1PTS 12500

// Swizzled LDS offset for a [64 rows][64 k] bf16 tile (layers 1-4).
__device__ __forceinline__ int swz(int r, int k) {
  return r * 64 + ((((k >> 3) ^ r) & 7) << 3) + (k & 7);
}

__global__ void prepack_w(const float* __restrict__ W, unsigned short* __restrict__ hi,
                          unsigned short* __restrict__ lo, int n) {
  int i = blockIdx.x * 256 + threadIdx.x;
  if (i >= n) return;
  float x = W[i];
  __bf16 h = (__bf16)x;
  __bf16 l = (__bf16)(x - (float)h);
  hi[i] = __builtin_bit_cast(unsigned short, h);
  lo[i] = __builtin_bit_cast(unsigned short, l);
}

// features f32 -> bf16 (rounded), 8 elems/thread
__global__ void prepack_feat(const float* __restrict__ F, unsigned short* __restrict__ out,
                             int n8) {
  int i = blockIdx.x * 256 + threadIdx.x;
  if (i >= n8) return;
  const float4* s = (const float4*)(F + (size_t)i * 8);
  float4 v0 = s[0], v1 = s[1];
  float x[8] = {v0.x, v0.y, v0.z, v0.w, v1.x, v1.y, v1.z, v1.w};
  u16x8 o;
#pragma unroll
  for (int e = 0; e < 8; ++e)
    o[e] = __builtin_bit_cast(unsigned short, (__bf16)x[e]);
  ((u16x8*)out)[i] = o;
}

__global__ void count_labels(const int* __restrict__ labels, int* __restrict__ cnt) {
  int i = blockIdx.x * 256 + threadIdx.x;
  if (i < NPTS) atomicAdd(&cnt[labels[i]], 1);
}

__global__ void finalize_pool(const int* __restrict__ pool, const int* __restrict__ cnt,
                              float* __restrict__ out) {
  int i = blockIdx.x * 256 + threadIdx.x;
  if (i >= N1PTS * 256) return;
  float denom = fmaxf((float)cnt[i >> 8], 1.0f);
  out[i] = ((float)pool[i]) * (1.0f / 16777216.0f) / denom;
}

// ---------------- Layer 0: direct-gather, LDS-free, no barriers ----------------
// out-tile per block: 64 rows x 256 cols. 4 waves, wave w owns cols [64w,64w+64).
// A (gathered bf16 features) and B (split bf16 weights) loaded straight into
// MFMA fragment registers (b128, fragment-native addressing).
__global__ __launch_bounds__(256) void conv0_gemm(
    const unsigned short* __restrict__ Fhi, const int* __restrict__ idx,
    const int* __restrict__ lab, const unsigned short* __restrict__ Whi,
    const unsigned short* __restrict__ Wlo, const float* __restrict__ bias,
    int* __restrict__ pool) {
  const int t = threadIdx.x;
  const int w = t >> 6, l = t & 63;
  const int lr = l & 15, lh = l >> 4;
  const int row0 = blockIdx.x * 64;

  f32x4 acc[4][4] = {};
  int prow[4], nb[4];
#pragma unroll
  for (int m = 0; m < 4; ++m) prow[m] = row0 + m * 16 + lr;

  const unsigned short* wh[4];
  const unsigned short* wl[4];
#pragma unroll
  for (int n = 0; n < 4; ++n) {
    const int co = w * 64 + n * 16 + lr;
    wh[n] = Whi + (size_t)co * 2048;
    wl[n] = Wlo + (size_t)co * 2048;
  }

#pragma unroll 1
  for (int j = 0; j < 8; ++j) {
#pragma unroll
    for (int m = 0; m < 4; ++m)
      nb[m] = (prow[m] < NPTS) ? idx[prow[m] * 8 + j] : -1;
#pragma unroll
    for (int kq = 0; kq < 4; ++kq) {
#pragma unroll
      for (int s = 0; s < 2; ++s) {
        const int cb = kq * 64 + s * 32 + lh * 8;  // channel offset 0..255
        const int kk = j * 256 + cb;               // global k
        bf16x8 a[4];
#pragma unroll
        for (int m = 0; m < 4; ++m) {
          bf16x8 av = {};
          if (nb[m] >= 0) av = *(const bf16x8*)(Fhi + ((size_t)nb[m] << 8) + cb);
          a[m] = av;
        }
#pragma unroll
        for (int n = 0; n < 4; ++n) {
          const bf16x8 bh = *(const bf16x8*)(wh[n] + kk);
          const bf16x8 bl = *(const bf16x8*)(wl[n] + kk);
#pragma unroll
          for (int m = 0; m < 4; ++m) {
            acc[m][n] = __builtin_amdgcn_mfma_f32_16x16x32_bf16(a[m], bh, acc[m][n], 0, 0, 0);
            acc[m][n] = __builtin_amdgcn_mfma_f32_16x16x32_bf16(a[m], bl, acc[m][n], 0, 0, 0);
          }
        }
      }
    }
  }

  // epilogue: C frag: col = lane&15, row = (lane>>4)*4 + reg
  float bv[4];
#pragma unroll
  for (int n = 0; n < 4; ++n) bv[n] = bias[w * 64 + n * 16 + lr];
#pragma unroll
  for (int m = 0; m < 4; ++m) {
#pragma unroll
    for (int r = 0; r < 4; ++r) {
      const int i = row0 + m * 16 + lh * 4 + r;
      if (i < NPTS) {
        const int lb = lab[i];
#pragma unroll
        for (int n = 0; n < 4; ++n) {
          float z = acc[m][n][r] + bv[n];
          z = 1.0f / (1.0f + expf(-z));
          atomicAdd(&pool[(size_t)lb * 256 + (w * 64 + n * 16 + lr)],
                    __float2int_rn(z * 16777216.0f));
        }
      }
    }
  }
}

// ---------------- Layers 1-4: LDS-staged 3-term-split GEMM (unchanged) --------
template <bool ACT, bool COMPOSED>
__global__ __launch_bounds__(256, 2) void conv_gemm(
    const float* __restrict__ act_in, const int* __restrict__ idx,
    const int* __restrict__ lab, const unsigned short* __restrict__ Whi,
    const unsigned short* __restrict__ Wlo, const float* __restrict__ bias,
    float* __restrict__ out,
    int M, int cinShift, int Cout, int Ktot) {
  __shared__ unsigned short sAhi[4096];
  __shared__ unsigned short sAlo[4096];
  __shared__ unsigned short sBhi[4096];
  __shared__ unsigned short sBlo[4096];

  const int Cin = 1 << cinShift;
  const int t = threadIdx.x;
  const int bm = blockIdx.x, bn = blockIdx.y;

  const int sr = t >> 2;
  const int kseg = (t & 3) << 4;
  const int ai = bm * 64 + sr;
  const int bco = bn * 64 + sr;

  f32x4 acc[4] = {};

  const int nch = Ktot >> 6;
  for (int kc = 0; kc < nch; ++kc) {
    const int kg = (kc << 6) + kseg;

    float va[16];
#pragma unroll
    for (int e = 0; e < 16; ++e) va[e] = 0.0f;
    if (ai < M) {
      int j = kg >> cinShift;
      int nbv = idx[ai * 8 + j];
      if (COMPOSED) nbv = lab[nbv];
      const float* src = act_in + ((size_t)nbv << cinShift) + (kg & (Cin - 1));
      const float4* s4 = (const float4*)src;
#pragma unroll
      for (int q = 0; q < 4; ++q) {
        float4 v = s4[q];
        va[q * 4 + 0] = v.x; va[q * 4 + 1] = v.y;
        va[q * 4 + 2] = v.z; va[q * 4 + 3] = v.w;
      }
    }
    bf16x8 h0, h1, l0, l1;
#pragma unroll
    for (int e = 0; e < 8; ++e) {
      float x0 = va[e], x1 = va[e + 8];
      __bf16 a = (__bf16)x0; h0[e] = a; l0[e] = (__bf16)(x0 - (float)a);
      __bf16 b = (__bf16)x1; h1[e] = b; l1[e] = (__bf16)(x1 - (float)b);
    }

    u16x8 bh0 = {}, bh1 = {}, bl0 = {}, bl1 = {};
    if (bco < Cout) {
      const unsigned short* sw = Whi + (size_t)bco * Ktot + kg;
      bh0 = ((const u16x8*)sw)[0];
      bh1 = ((const u16x8*)sw)[1];
      const unsigned short* sl = Wlo + (size_t)bco * Ktot + kg;
      bl0 = ((const u16x8*)sl)[0];
      bl1 = ((const u16x8*)sl)[1];
    }

    __syncthreads();
    const int w0 = swz(sr, kseg), w1 = swz(sr, kseg + 8);
    *(bf16x8*)&sAhi[w0] = h0; *(bf16x8*)&sAhi[w1] = h1;
    *(u16x8*)&sBhi[w0] = bh0; *(u16x8*)&sBhi[w1] = bh1;
    *(bf16x8*)&sAlo[w0] = l0; *(bf16x8*)&sAlo[w1] = l1;
    *(u16x8*)&sBlo[w0] = bl0; *(u16x8*)&sBlo[w1] = bl1;
    __syncthreads();

    const int l = t & 63;
    const int lr = l & 15, lh = l >> 4;
    const int wid = t >> 6;
#pragma unroll
    for (int s = 0; s < 2; ++s) {
      const int kb = s * 32 + lh * 8;
      const int boff = swz(wid * 16 + lr, kb);
      bf16x8 bh = *(const bf16x8*)&sBhi[boff];
#pragma unroll
      for (int m = 0; m < 4; ++m) {
        const int aoff = swz(m * 16 + lr, kb);
        bf16x8 ah = *(const bf16x8*)&sAhi[aoff];
        acc[m] = __builtin_amdgcn_mfma_f32_16x16x32_bf16(ah, bh, acc[m], 0, 0, 0);
        bf16x8 bl = *(const bf16x8*)&sBlo[boff];
        bf16x8 al = *(const bf16x8*)&sAlo[aoff];
        acc[m] = __builtin_amdgcn_mfma_f32_16x16x32_bf16(ah, bl, acc[m], 0, 0, 0);
        acc[m] = __builtin_amdgcn_mfma_f32_16x16x32_bf16(al, bh, acc[m], 0, 0, 0);
      }
    }
  }

  const int l = t & 63, wid = t >> 6;
  const int lr = l & 15, lh = l >> 4;
  const int co = bn * 64 + wid * 16 + lr;
  if (co < Cout) {
    const float bvv = bias[co];
#pragma unroll
    for (int m = 0; m < 4; ++m) {
#pragma unroll
      for (int r = 0; r < 4; ++r) {
        const int i = bm * 64 + m * 16 + lh * 4 + r;
        if (i < M) {
          float z = acc[m][r] + bvv;
          if (ACT) z = 1.0f / (1.0f + expf(-z));
          out[(size_t)i * Cout + co] = z;
        }
      }
    }
  }
}

extern "C" void kernel_launch(void* const* d_in, const int* in_sizes, int n_in,
                              void* d_out, int out_size, void* d_ws, size_t ws_size,
                              hipStream_t stream) {
  const float* features = (const float*)d_in[0];
  const int* knn0 = (const int*)d_in[1];
  const int* knn1 = (const int*)d_in[2];
  const int* labels = (const int*)d_in[3];
  const float* kw[5] = {(const float*)d_in[4], (const float*)d_in[6],
                        (const float*)d_in[8], (const float*)d_in[10],
                        (const float*)d_in[12]};
  const float* bw[5] = {(const float*)d_in[5], (const float*)d_in[7],
                        (const float*)d_in[9], (const float*)d_in[11],
                        (const float*)d_in[13]};

  char* ws = (char*)d_ws;
  size_t off = 0;
  auto alloc = [&](size_t bytes) -> void* {
    void* p = ws + off;
    off = (off + bytes + 255) & ~(size_t)255;
    return p;
  };
  const int wsz[5] = {524288, 262144, 65536, 16384, 768};
  const int wtotal = 869120;
  unsigned short* Whi = (unsigned short*)alloc((size_t)wtotal * 2);
  unsigned short* Wlo = (unsigned short*)alloc((size_t)wtotal * 2);
  int* pool = (int*)alloc((size_t)N1PTS * 256 * 4);   // N1*256*4 is 256-aligned
  int* cnt = (int*)alloc((size_t)N1PTS * 4);
  float* pooled = (float*)alloc((size_t)N1PTS * 256 * 4);
  float* f1 = (float*)alloc((size_t)N1PTS * 128 * 4);
  float* f2 = (float*)alloc((size_t)N1PTS * 64 * 4);
  unsigned short* Fhi = (unsigned short*)alloc((size_t)NPTS * 256 * 2);
  float* f3 = (float*)pool;  // alias: pool's last read (finalize) precedes layer 3
  if (off > ws_size) return;

  // 1. prepack weights (hi/lo) and features (hi only)
  size_t woff = 0;
  for (int i = 0; i < 5; ++i) {
    prepack_w<<<(wsz[i] + 255) / 256, 256, 0, stream>>>(kw[i], Whi + woff, Wlo + woff, wsz[i]);
    woff += wsz[i];
  }
  prepack_feat<<<(NPTS * 256 / 8 + 255) / 256, 256, 0, stream>>>(features, Fhi, NPTS * 256 / 8);

  // 2. zero pool + cnt (contiguous), histogram labels
  hipMemsetAsync(pool, 0, (size_t)N1PTS * 256 * 4 + (size_t)N1PTS * 4, stream);
  count_labels<<<(NPTS + 255) / 256, 256, 0, stream>>>(labels, cnt);

  // 3. layer 0: direct-gather GEMM + fused fixed-point pool scatter
  conv0_gemm<<<1563, 256, 0, stream>>>(Fhi, knn0, labels, Whi, Wlo, bw[0], pool);

  // 4. pooled mean [N1,256]
  finalize_pool<<<(N1PTS * 256 + 255) / 256, 256, 0, stream>>>(pool, cnt, pooled);

  dim3 blk(256);
  // 5. layer 1: pooled -> f1 [N1,128]
  conv_gemm<true, false><<<dim3(196, 2), blk, 0, stream>>>(
      pooled, knn1, labels, Whi + 524288, Wlo + 524288, bw[1], f1,
      N1PTS, 8, 128, 2048);

  // 6. layer 2: f1 -> f2 [N1,64]
  conv_gemm<true, false><<<dim3(196, 1), blk, 0, stream>>>(
      f1, knn1, labels, Whi + 786432, Wlo + 786432, bw[2], f2,
      N1PTS, 7, 64, 1024);

  // 7. layer 3: gather f2[labels[knn0]] -> f3 [N,32]
  conv_gemm<true, true><<<dim3(1563, 1), blk, 0, stream>>>(
      f2, knn0, labels, Whi + 851968, Wlo + 851968, bw[3], f3,
      NPTS, 6, 32, 512);

  // 8. layer 4: f3 -> out [N,3], no activation
  conv_gemm<false, false><<<dim3(1563, 1), blk, 0, stream>>>(
      f3, knn0, labels, Whi + 868352, Wlo + 868352, bw[4], (float*)d_out,
      NPTS, 5, 3, 256);
}

// Round 3
// 851.427 us; speedup vs baseline: 1.0206x; 1.0206x over previous
//
#include <hip/hip_runtime.h>
#include <hip/hip_bf16.h>

// GaussianConv: 5-layer KNN conv net on point cloud.
// R3: layer 0 = gathered-A-via-global_load_lds (swizzled, dbuf) +
// fragment-packed coalesced B direct-to-register, 128x256 tile, 8 waves.
// Weights 2-term hi/lo split; features prepacked bf16.
// Layers 1-4 unchanged (LDS 3-term kernel, ~120us total).

typedef __attribute__((ext_vector_type(8))) __bf16 bf16x8;
typedef __attribute__((ext_vector_type(4))) float f32x4;
typedef __attribute__((ext_vector_type(8))) unsigned short u16x8;

#define NPTS 100000
#define N1PTS 12500

__device__ __forceinline__ void gload_lds16(const unsigned short* g, unsigned short* l) {
  __builtin_amdgcn_global_load_lds(
      (const __attribute__((address_space(1))) void*)g,
      (__attribute__((address_space(3))) void*)l, 16, 0, 0);
}

// Swizzled LDS offset for [64 rows][64 k] bf16 tiles (layers 1-4 kernel).
__device__ __forceinline__ int swz(int r, int k) {
  return r * 64 + ((((k >> 3) ^ r) & 7) << 3) + (k & 7);
}

__global__ void prepack_w(const float* __restrict__ W, unsigned short* __restrict__ hi,
                          unsigned short* __restrict__ lo, int n) {
  int i = blockIdx.x * 256 + threadIdx.x;
  if (i >= n) return;
  float x = W[i];
  __bf16 h = (__bf16)x;
  __bf16 l = (__bf16)(x - (float)h);
  hi[i] = __builtin_bit_cast(unsigned short, h);
  lo[i] = __builtin_bit_cast(unsigned short, l);
}

// Layer-0 weights -> MFMA-fragment-native packed order:
// dest[(((c*16+nb)*2+s)*64+lane)*8+e] = W[nb*16+(lane&15)][c*64+s*32+(lane>>4)*8+e]
__global__ void prepack_w0(const float* __restrict__ W,
                           unsigned short* __restrict__ hi,
                           unsigned short* __restrict__ lo) {
  const int tid = blockIdx.x * 256 + threadIdx.x;  // 65536 total
  const int lane = tid & 63;
  const int s = (tid >> 6) & 1;
  const int nb = (tid >> 7) & 15;
  const int c = tid >> 11;  // 0..31
  const int co = nb * 16 + (lane & 15);
  const int k = c * 64 + s * 32 + ((lane >> 4) << 3);
  const float* src = W + (size_t)co * 2048 + k;
  u16x8 h, lw;
#pragma unroll
  for (int e = 0; e < 8; ++e) {
    float x = src[e];
    __bf16 hb = (__bf16)x;
    h[e] = __builtin_bit_cast(unsigned short, hb);
    lw[e] = __builtin_bit_cast(unsigned short, (__bf16)(x - (float)hb));
  }
  ((u16x8*)hi)[tid] = h;
  ((u16x8*)lo)[tid] = lw;
}

// features f32 -> bf16 rounded, 8 elems/thread
__global__ void prepack_feat(const float* __restrict__ F, unsigned short* __restrict__ out,
                             int n8) {
  int i = blockIdx.x * 256 + threadIdx.x;
  if (i >= n8) return;
  const float4* s = (const float4*)(F + (size_t)i * 8);
  float4 v0 = s[0], v1 = s[1];
  float x[8] = {v0.x, v0.y, v0.z, v0.w, v1.x, v1.y, v1.z, v1.w};
  u16x8 o;
#pragma unroll
  for (int e = 0; e < 8; ++e)
    o[e] = __builtin_bit_cast(unsigned short, (__bf16)x[e]);
  ((u16x8*)out)[i] = o;
}

__global__ void count_labels(const int* __restrict__ labels, int* __restrict__ cnt) {
  int i = blockIdx.x * 256 + threadIdx.x;
  if (i < NPTS) atomicAdd(&cnt[labels[i]], 1);
}

__global__ void finalize_pool(const int* __restrict__ pool, const int* __restrict__ cnt,
                              float* __restrict__ out) {
  int i = blockIdx.x * 256 + threadIdx.x;
  if (i >= N1PTS * 256) return;
  float denom = fmaxf((float)cnt[i >> 8], 1.0f);
  out[i] = ((float)pool[i]) * (1.0f / 16777216.0f) / denom;
}

// ---------------- Layer 0 ----------------
// 782 blocks x 512 thr. Tile 128 rows x 256 cols; wave (wr,wc) of 2x4 grid
// owns rows [wr*64,+64) x cols [wc*64,+64) -> acc[4][4] frags.
// Per 64-k chunk: A gathered into LDS via global_load_lds (seg-XOR swizzle,
// double-buffered), B read straight to regs from fragment-packed weights.
__global__ __launch_bounds__(512) void conv0_gemm(
    const unsigned short* __restrict__ Fhi, const int* __restrict__ idx,
    const int* __restrict__ lab, const unsigned short* __restrict__ Wpk_hi,
    const unsigned short* __restrict__ Wpk_lo, const float* __restrict__ bias,
    int* __restrict__ pool) {
  __shared__ unsigned short sA[2][128 * 64];  // 16KB x2

  const int t = threadIdx.x;
  const int w = t >> 6, l = t & 63;
  const int lr = l & 15, lh = l >> 4;
  const int wr = w >> 2, wc = w & 3;
  const int row0 = blockIdx.x * 128;

  // staging geometry: wave stages rows [w*16, w*16+16) as 2x 1KB gll
  const int srow = l >> 3;                       // 0..7 within 8-row group
  const int sseg_src = (l & 7) ^ (srow & 7);     // source seg for dest seg l&7

  f32x4 acc[4][4] = {};

  auto load_nb = [&](int c, int q) -> int {
    const int grow = row0 + w * 16 + q * 8 + srow;
    return (grow < NPTS) ? idx[grow * 8 + (c >> 2)] : 0;
  };
  auto stage = [&](int c, int b, int nb0, int nb1) {
    const int cb = (c & 3) << 6;
#pragma unroll
    for (int q = 0; q < 2; ++q) {
      const int nb = q ? nb1 : nb0;
      const unsigned short* gp = Fhi + ((size_t)nb << 8) + cb + sseg_src * 8;
      unsigned short* lp = &sA[b][(w * 16 + q * 8) * 64];
      gload_lds16(gp, lp);
    }
  };

  // prologue: stage chunk 0 (latency exposed once), prefetch idx for chunk 1
  stage(0, 0, load_nb(0, 0), load_nb(0, 1));
  int nbp0 = load_nb(1, 0), nbp1 = load_nb(1, 1);
  __syncthreads();

  for (int c = 0; c < 32; ++c) {
    const int b = c & 1;
    // idx prefetch for staging chunk c+2 (hidden under this whole chunk)
    int nbn0 = 0, nbn1 = 0;
    if (c + 2 < 32) { nbn0 = load_nb(c + 2, 0); nbn1 = load_nb(c + 2, 1); }

    // B fragment loads: coalesced 1KB/wave-instr from packed weights
    bf16x8 bh[2][4], bl[2][4];
#pragma unroll
    for (int s = 0; s < 2; ++s)
#pragma unroll
      for (int n = 0; n < 4; ++n) {
        const size_t base = (((size_t)(c * 16 + wc * 4 + n) * 2 + s) * 64 + l) * 8;
        bh[s][n] = *(const bf16x8*)(Wpk_hi + base);
        bl[s][n] = *(const bf16x8*)(Wpk_lo + base);
      }

    // A prefetch for chunk c+1 into other buffer (issued after B so B's
    // vmcnt waits never drain it)
    if (c < 31) stage(c + 1, b ^ 1, nbp0, nbp1);

#pragma unroll
    for (int s = 0; s < 2; ++s) {
      bf16x8 a[4];
#pragma unroll
      for (int m = 0; m < 4; ++m) {
        const int rl = wr * 64 + m * 16 + lr;
        const int seg = ((s << 2) + lh) ^ (lr & 7);
        a[m] = *(const bf16x8*)&sA[b][rl * 64 + seg * 8];
      }
#pragma unroll
      for (int n = 0; n < 4; ++n)
#pragma unroll
        for (int m = 0; m < 4; ++m) {
          acc[m][n] = __builtin_amdgcn_mfma_f32_16x16x32_bf16(a[m], bh[s][n], acc[m][n], 0, 0, 0);
          acc[m][n] = __builtin_amdgcn_mfma_f32_16x16x32_bf16(a[m], bl[s][n], acc[m][n], 0, 0, 0);
        }
    }
    __syncthreads();
    nbp0 = nbn0; nbp1 = nbn1;
  }

  // epilogue: C frag col = lane&15, row = (lane>>4)*4 + r
  float bv[4];
#pragma unroll
  for (int n = 0; n < 4; ++n) bv[n] = bias[wc * 64 + n * 16 + lr];
#pragma unroll
  for (int m = 0; m < 4; ++m) {
#pragma unroll
    for (int r = 0; r < 4; ++r) {
      const int i = row0 + wr * 64 + m * 16 + lh * 4 + r;
      if (i < NPTS) {
        const int lb = lab[i];
#pragma unroll
        for (int n = 0; n < 4; ++n) {
          float z = acc[m][n][r] + bv[n];
          z = 1.0f / (1.0f + expf(-z));
          atomicAdd(&pool[(size_t)lb * 256 + (wc * 64 + n * 16 + lr)],
                    __float2int_rn(z * 16777216.0f));
        }
      }
    }
  }
}

// ---------------- Layers 1-4: LDS-staged 3-term-split GEMM ----------------
template <bool ACT, bool COMPOSED>
__global__ __launch_bounds__(256, 2) void conv_gemm(
    const float* __restrict__ act_in, const int* __restrict__ idx,
    const int* __restrict__ lab, const unsigned short* __restrict__ Whi,
    const unsigned short* __restrict__ Wlo, const float* __restrict__ bias,
    float* __restrict__ out,
    int M, int cinShift, int Cout, int Ktot) {
  __shared__ unsigned short sAhi[4096];
  __shared__ unsigned short sAlo[4096];
  __shared__ unsigned short sBhi[4096];
  __shared__ unsigned short sBlo[4096];

  const int Cin = 1 << cinShift;
  const int t = threadIdx.x;
  const int bm = blockIdx.x, bn = blockIdx.y;

  const int sr = t >> 2;
  const int kseg = (t & 3) << 4;
  const int ai = bm * 64 + sr;
  const int bco = bn * 64 + sr;

  f32x4 acc[4] = {};

  const int nch = Ktot >> 6;
  for (int kc = 0; kc < nch; ++kc) {
    const int kg = (kc << 6) + kseg;

    float va[16];
#pragma unroll
    for (int e = 0; e < 16; ++e) va[e] = 0.0f;
    if (ai < M) {
      int j = kg >> cinShift;
      int nbv = idx[ai * 8 + j];
      if (COMPOSED) nbv = lab[nbv];
      const float* src = act_in + ((size_t)nbv << cinShift) + (kg & (Cin - 1));
      const float4* s4 = (const float4*)src;
#pragma unroll
      for (int q = 0; q < 4; ++q) {
        float4 v = s4[q];
        va[q * 4 + 0] = v.x; va[q * 4 + 1] = v.y;
        va[q * 4 + 2] = v.z; va[q * 4 + 3] = v.w;
      }
    }
    bf16x8 h0, h1, l0, l1;
#pragma unroll
    for (int e = 0; e < 8; ++e) {
      float x0 = va[e], x1 = va[e + 8];
      __bf16 a = (__bf16)x0; h0[e] = a; l0[e] = (__bf16)(x0 - (float)a);
      __bf16 b = (__bf16)x1; h1[e] = b; l1[e] = (__bf16)(x1 - (float)b);
    }

    u16x8 bh0 = {}, bh1 = {}, bl0 = {}, bl1 = {};
    if (bco < Cout) {
      const unsigned short* sw = Whi + (size_t)bco * Ktot + kg;
      bh0 = ((const u16x8*)sw)[0];
      bh1 = ((const u16x8*)sw)[1];
      const unsigned short* sl = Wlo + (size_t)bco * Ktot + kg;
      bl0 = ((const u16x8*)sl)[0];
      bl1 = ((const u16x8*)sl)[1];
    }

    __syncthreads();
    const int w0 = swz(sr, kseg), w1 = swz(sr, kseg + 8);
    *(bf16x8*)&sAhi[w0] = h0; *(bf16x8*)&sAhi[w1] = h1;
    *(u16x8*)&sBhi[w0] = bh0; *(u16x8*)&sBhi[w1] = bh1;
    *(bf16x8*)&sAlo[w0] = l0; *(bf16x8*)&sAlo[w1] = l1;
    *(u16x8*)&sBlo[w0] = bl0; *(u16x8*)&sBlo[w1] = bl1;
    __syncthreads();

    const int l = t & 63;
    const int lr = l & 15, lh = l >> 4;
    const int wid = t >> 6;
#pragma unroll
    for (int s = 0; s < 2; ++s) {
      const int kb = s * 32 + lh * 8;
      const int boff = swz(wid * 16 + lr, kb);
      bf16x8 bh = *(const bf16x8*)&sBhi[boff];
#pragma unroll
      for (int m = 0; m < 4; ++m) {
        const int aoff = swz(m * 16 + lr, kb);
        bf16x8 ah = *(const bf16x8*)&sAhi[aoff];
        acc[m] = __builtin_amdgcn_mfma_f32_16x16x32_bf16(ah, bh, acc[m], 0, 0, 0);
        bf16x8 bl = *(const bf16x8*)&sBlo[boff];
        bf16x8 al = *(const bf16x8*)&sAlo[aoff];
        acc[m] = __builtin_amdgcn_mfma_f32_16x16x32_bf16(ah, bl, acc[m], 0, 0, 0);
        acc[m] = __builtin_amdgcn_mfma_f32_16x16x32_bf16(al, bh, acc[m], 0, 0, 0);
      }
    }
  }

  const int l = t & 63, wid = t >> 6;
  const int lr = l & 15, lh = l >> 4;
  const int co = bn * 64 + wid * 16 + lr;
  if (co < Cout) {
    const float bvv = bias[co];
#pragma unroll
    for (int m = 0; m < 4; ++m) {
#pragma unroll
      for (int r = 0; r < 4; ++r) {
        const int i = bm * 64 + m * 16 + lh * 4 + r;
        if (i < M) {
          float z = acc[m][r] + bvv;
          if (ACT) z = 1.0f / (1.0f + expf(-z));
          out[(size_t)i * Cout + co] = z;
        }
      }
    }
  }
}

extern "C" void kernel_launch(void* const* d_in, const int* in_sizes, int n_in,
                              void* d_out, int out_size, void* d_ws, size_t ws_size,
                              hipStream_t stream) {
  const float* features = (const float*)d_in[0];
  const int* knn0 = (const int*)d_in[1];
  const int* knn1 = (const int*)d_in[2];
  const int* labels = (const int*)d_in[3];
  const float* kw[5] = {(const float*)d_in[4], (const float*)d_in[6],
                        (const float*)d_in[8], (const float*)d_in[10],
                        (const float*)d_in[12]};
  const float* bw[5] = {(const float*)d_in[5], (const float*)d_in[7],
                        (const float*)d_in[9], (const float*)d_in[11],
                        (const float*)d_in[13]};

  char* ws = (char*)d_ws;
  size_t off = 0;
  auto alloc = [&](size_t bytes) -> void* {
    void* p = ws + off;
    off = (off + bytes + 255) & ~(size_t)255;
    return p;
  };
  // layer-0 packed weights (fragment-native order)
  unsigned short* Wpk_hi = (unsigned short*)alloc((size_t)524288 * 2);
  unsigned short* Wpk_lo = (unsigned short*)alloc((size_t)524288 * 2);
  // layers 1-4 row-major hi/lo weights
  const int wsz14[4] = {262144, 65536, 16384, 768};
  const int woff14[4] = {0, 262144, 327680, 344064};
  const int wtot14 = 344832;
  unsigned short* Whi = (unsigned short*)alloc((size_t)wtot14 * 2);
  unsigned short* Wlo = (unsigned short*)alloc((size_t)wtot14 * 2);
  int* pool = (int*)alloc((size_t)N1PTS * 256 * 4);
  int* cnt = (int*)alloc((size_t)N1PTS * 4);
  float* pooled = (float*)alloc((size_t)N1PTS * 256 * 4);
  float* f1 = (float*)alloc((size_t)N1PTS * 128 * 4);
  float* f2 = (float*)alloc((size_t)N1PTS * 64 * 4);
  unsigned short* Fhi = (unsigned short*)alloc((size_t)NPTS * 256 * 2);
  float* f3 = (float*)pool;  // alias: pool fully consumed before layer 3
  if (off > ws_size) return;

  // 1. prepack weights + features
  prepack_w0<<<256, 256, 0, stream>>>(kw[0], Wpk_hi, Wpk_lo);
  for (int i = 0; i < 4; ++i)
    prepack_w<<<(wsz14[i] + 255) / 256, 256, 0, stream>>>(
        kw[i + 1], Whi + woff14[i], Wlo + woff14[i], wsz14[i]);
  prepack_feat<<<(NPTS * 256 / 8 + 255) / 256, 256, 0, stream>>>(features, Fhi, NPTS * 256 / 8);

  // 2. zero pool+cnt, histogram labels
  hipMemsetAsync(pool, 0, (size_t)N1PTS * 256 * 4 + (size_t)N1PTS * 4, stream);
  count_labels<<<(NPTS + 255) / 256, 256, 0, stream>>>(labels, cnt);

  // 3. layer 0 + fused fixed-point pool scatter
  conv0_gemm<<<782, 512, 0, stream>>>(Fhi, knn0, labels, Wpk_hi, Wpk_lo, bw[0], pool);

  // 4. pooled mean [N1,256]
  finalize_pool<<<(N1PTS * 256 + 255) / 256, 256, 0, stream>>>(pool, cnt, pooled);

  dim3 blk(256);
  // 5. layer 1
  conv_gemm<true, false><<<dim3(196, 2), blk, 0, stream>>>(
      pooled, knn1, labels, Whi + woff14[0], Wlo + woff14[0], bw[1], f1,
      N1PTS, 8, 128, 2048);
  // 6. layer 2
  conv_gemm<true, false><<<dim3(196, 1), blk, 0, stream>>>(
      f1, knn1, labels, Whi + woff14[1], Wlo + woff14[1], bw[2], f2,
      N1PTS, 7, 64, 1024);
  // 7. layer 3 (composed gather f2[labels[knn0]])
  conv_gemm<true, true><<<dim3(1563, 1), blk, 0, stream>>>(
      f2, knn0, labels, Whi + woff14[2], Wlo + woff14[2], bw[3], f3,
      NPTS, 6, 32, 512);
  // 8. layer 4 -> out
  conv_gemm<false, false><<<dim3(1563, 1), blk, 0, stream>>>(
      f3, knn0, labels, Whi + woff14[3], Wlo + woff14[3], bw[4], (float*)d_out,
      NPTS, 5, 3, 256);
}

// Round 4
// 372.506 us; speedup vs baseline: 2.3327x; 2.2857x over previous
//
#include <hip/hip_runtime.h>
#include <hip/hip_bf16.h>

// GaussianConv: 5-layer KNN conv net on point cloud.
// R4: whole net in f16 single-term MFMA (accuracy >= 2-term bf16 split,
// half the work). Layer 0: 64x256 tile, 256 thr, one-gather A via swizzled
// global_load_lds (dbuf), fragment-packed coalesced B direct-to-reg
// (1MB, L2-resident), ~6 blocks/CU resident for latency hiding.
// Pool fused as deterministic fixed-point atomics.

typedef __attribute__((ext_vector_type(8))) _Float16 f16x8;
typedef __attribute__((ext_vector_type(4))) float f32x4;
typedef __attribute__((ext_vector_type(8))) unsigned short u16x8;

#define NPTS 100000
#define N1PTS 12500

__device__ __forceinline__ void gload_lds16(const unsigned short* g, unsigned short* l) {
  __builtin_amdgcn_global_load_lds(
      (const __attribute__((address_space(1))) void*)g,
      (__attribute__((address_space(3))) void*)l, 16, 0, 0);
}

// Swizzled LDS offset for [64 rows][64 k] f16 tiles (layers 1-4 kernel).
__device__ __forceinline__ int swz(int r, int k) {
  return r * 64 + ((((k >> 3) ^ r) & 7) << 3) + (k & 7);
}

__device__ __forceinline__ unsigned short f16bits(float x) {
  return __builtin_bit_cast(unsigned short, (_Float16)x);
}

// layers 1-4 weights: f32 -> f16 row-major
__global__ void prepack_w(const float* __restrict__ W, unsigned short* __restrict__ out,
                          int n) {
  int i = blockIdx.x * 256 + threadIdx.x;
  if (i < n) out[i] = f16bits(W[i]);
}

// Layer-0 weights -> MFMA-fragment-native packed f16:
// group g = (((c*4 + w)*4 + n)*2 + s), lane l, elem e:
//   dest[g*512 + l*8 + e] = W[w*64+n*16+(l&15)][c*64 + s*32 + (l>>4)*8 + e]
__global__ void prepack_w0(const float* __restrict__ W, unsigned short* __restrict__ out) {
  const int tid = blockIdx.x * 256 + threadIdx.x;  // 65536 total
  const int l = tid & 63;
  const int s = (tid >> 6) & 1;
  const int n = (tid >> 7) & 3;
  const int w = (tid >> 9) & 3;
  const int c = tid >> 11;  // 0..31
  const int co = w * 64 + n * 16 + (l & 15);
  const int k = c * 64 + s * 32 + ((l >> 4) << 3);
  const float* src = W + (size_t)co * 2048 + k;
  u16x8 h;
#pragma unroll
  for (int e = 0; e < 8; ++e) h[e] = f16bits(src[e]);
  ((u16x8*)out)[tid] = h;
}

// features f32 -> f16, 8 elems/thread
__global__ void prepack_feat(const float* __restrict__ F, unsigned short* __restrict__ out,
                             int n8) {
  int i = blockIdx.x * 256 + threadIdx.x;
  if (i >= n8) return;
  const float4* s = (const float4*)(F + (size_t)i * 8);
  float4 v0 = s[0], v1 = s[1];
  float x[8] = {v0.x, v0.y, v0.z, v0.w, v1.x, v1.y, v1.z, v1.w};
  u16x8 o;
#pragma unroll
  for (int e = 0; e < 8; ++e) o[e] = f16bits(x[e]);
  ((u16x8*)out)[i] = o;
}

__global__ void count_labels(const int* __restrict__ labels, int* __restrict__ cnt) {
  int i = blockIdx.x * 256 + threadIdx.x;
  if (i < NPTS) atomicAdd(&cnt[labels[i]], 1);
}

__global__ void finalize_pool(const int* __restrict__ pool, const int* __restrict__ cnt,
                              float* __restrict__ out) {
  int i = blockIdx.x * 256 + threadIdx.x;
  if (i >= N1PTS * 256) return;
  float denom = fmaxf((float)cnt[i >> 8], 1.0f);
  out[i] = ((float)pool[i]) * (1.0f / 16777216.0f) / denom;
}

// ---------------- Layer 0 ----------------
// 1563 blocks x 256 thr (4 waves). Tile 64 rows x 256 cols; wave w owns cols
// [w*64,+64) -> acc[4][4]. A (gathered f16 features) staged once per 64-k
// chunk via seg-XOR-swizzled global_load_lds, double-buffered; B read
// coalesced straight to regs from fragment-packed weights (L2-resident 1MB).
__global__ __launch_bounds__(256) void conv0_gemm(
    const unsigned short* __restrict__ F16, const int* __restrict__ idx,
    const int* __restrict__ lab, const unsigned short* __restrict__ Wpk,
    const float* __restrict__ bias, int* __restrict__ pool) {
  __shared__ unsigned short sA[2][64 * 64];  // 8KB x2

  const int t = threadIdx.x;
  const int w = t >> 6, l = t & 63;
  const int lr = l & 15, lh = l >> 4;
  const int row0 = blockIdx.x * 64;

  // staging geometry: wave w stages rows [w*16, +16) as 2x 1KB gll
  const int srow = l >> 3;                    // row within 8-row group
  const int sseg_src = (l & 7) ^ (srow & 7);  // XOR seg swizzle (source side)

  f32x4 acc[4][4] = {};

  auto load_nb = [&](int c, int q) -> int {
    const int grow = row0 + w * 16 + q * 8 + srow;
    return (grow < NPTS) ? idx[grow * 8 + (c >> 2)] : 0;
  };
  auto stage = [&](int c, int b, int nb0, int nb1) {
    const int cb = (c & 3) << 6;  // channel offset within row
#pragma unroll
    for (int q = 0; q < 2; ++q) {
      const int nb = q ? nb1 : nb0;
      const unsigned short* gp = F16 + ((size_t)nb << 8) + cb + sseg_src * 8;
      unsigned short* lp = &sA[b][(w * 16 + q * 8) * 64];
      gload_lds16(gp, lp);
    }
  };

  // prologue
  stage(0, 0, load_nb(0, 0), load_nb(0, 1));
  int nbp0 = load_nb(1, 0), nbp1 = load_nb(1, 1);
  __syncthreads();

  for (int c = 0; c < 32; ++c) {
    const int b = c & 1;
    int nbn0 = 0, nbn1 = 0;
    if (c + 2 < 32) { nbn0 = load_nb(c + 2, 0); nbn1 = load_nb(c + 2, 1); }

    // B fragments: coalesced 1KB/wave-instr
    f16x8 bh[2][4];
#pragma unroll
    for (int s = 0; s < 2; ++s)
#pragma unroll
      for (int n = 0; n < 4; ++n) {
        const size_t base = ((((size_t)c * 4 + w) * 4 + n) * 2 + s) * 512 + (size_t)l * 8;
        bh[s][n] = *(const f16x8*)(Wpk + base);
      }

    // A prefetch for next chunk (after B so B's vmcnt waits keep it in flight)
    if (c < 31) stage(c + 1, b ^ 1, nbp0, nbp1);

#pragma unroll
    for (int s = 0; s < 2; ++s) {
      f16x8 a[4];
#pragma unroll
      for (int m = 0; m < 4; ++m) {
        const int rl = m * 16 + lr;
        const int seg = ((s << 2) + lh) ^ (lr & 7);
        a[m] = *(const f16x8*)&sA[b][rl * 64 + seg * 8];
      }
#pragma unroll
      for (int n = 0; n < 4; ++n)
#pragma unroll
        for (int m = 0; m < 4; ++m)
          acc[m][n] = __builtin_amdgcn_mfma_f32_16x16x32_f16(a[m], bh[s][n], acc[m][n], 0, 0, 0);
    }
    __syncthreads();
    nbp0 = nbn0; nbp1 = nbn1;
  }

  // epilogue: C frag col = lane&15, row = (lane>>4)*4 + r
  float bv[4];
#pragma unroll
  for (int n = 0; n < 4; ++n) bv[n] = bias[w * 64 + n * 16 + lr];
#pragma unroll
  for (int m = 0; m < 4; ++m) {
#pragma unroll
    for (int r = 0; r < 4; ++r) {
      const int i = row0 + m * 16 + lh * 4 + r;
      if (i < NPTS) {
        const int lb = lab[i];
#pragma unroll
        for (int n = 0; n < 4; ++n) {
          float z = acc[m][n][r] + bv[n];
          z = 1.0f / (1.0f + expf(-z));
          atomicAdd(&pool[(size_t)lb * 256 + (w * 64 + n * 16 + lr)],
                    __float2int_rn(z * 16777216.0f));
        }
      }
    }
  }
}

// ---------------- Layers 1-4: LDS-staged f16 GEMM ----------------
template <bool ACT, bool COMPOSED>
__global__ __launch_bounds__(256, 2) void conv_gemm(
    const float* __restrict__ act_in, const int* __restrict__ idx,
    const int* __restrict__ lab, const unsigned short* __restrict__ Wf,
    const float* __restrict__ bias, float* __restrict__ out,
    int M, int cinShift, int Cout, int Ktot) {
  __shared__ unsigned short sAh[4096];
  __shared__ unsigned short sBh[4096];

  const int Cin = 1 << cinShift;
  const int t = threadIdx.x;
  const int bm = blockIdx.x, bn = blockIdx.y;

  const int sr = t >> 2;
  const int kseg = (t & 3) << 4;
  const int ai = bm * 64 + sr;
  const int bco = bn * 64 + sr;

  f32x4 acc[4] = {};

  const int nch = Ktot >> 6;
  for (int kc = 0; kc < nch; ++kc) {
    const int kg = (kc << 6) + kseg;

    float va[16];
#pragma unroll
    for (int e = 0; e < 16; ++e) va[e] = 0.0f;
    if (ai < M) {
      int j = kg >> cinShift;
      int nbv = idx[ai * 8 + j];
      if (COMPOSED) nbv = lab[nbv];
      const float* src = act_in + ((size_t)nbv << cinShift) + (kg & (Cin - 1));
      const float4* s4 = (const float4*)src;
#pragma unroll
      for (int q = 0; q < 4; ++q) {
        float4 v = s4[q];
        va[q * 4 + 0] = v.x; va[q * 4 + 1] = v.y;
        va[q * 4 + 2] = v.z; va[q * 4 + 3] = v.w;
      }
    }
    u16x8 h0, h1;
#pragma unroll
    for (int e = 0; e < 8; ++e) {
      h0[e] = f16bits(va[e]);
      h1[e] = f16bits(va[e + 8]);
    }

    u16x8 bh0 = {}, bh1 = {};
    if (bco < Cout) {
      const unsigned short* sw = Wf + (size_t)bco * Ktot + kg;
      bh0 = ((const u16x8*)sw)[0];
      bh1 = ((const u16x8*)sw)[1];
    }

    __syncthreads();
    const int w0 = swz(sr, kseg), w1 = swz(sr, kseg + 8);
    *(u16x8*)&sAh[w0] = h0; *(u16x8*)&sAh[w1] = h1;
    *(u16x8*)&sBh[w0] = bh0; *(u16x8*)&sBh[w1] = bh1;
    __syncthreads();

    const int l = t & 63;
    const int lr = l & 15, lh = l >> 4;
    const int wid = t >> 6;
#pragma unroll
    for (int s = 0; s < 2; ++s) {
      const int kb = s * 32 + lh * 8;
      const int boff = swz(wid * 16 + lr, kb);
      f16x8 bh = *(const f16x8*)&sBh[boff];
#pragma unroll
      for (int m = 0; m < 4; ++m) {
        const int aoff = swz(m * 16 + lr, kb);
        f16x8 ah = *(const f16x8*)&sAh[aoff];
        acc[m] = __builtin_amdgcn_mfma_f32_16x16x32_f16(ah, bh, acc[m], 0, 0, 0);
      }
    }
  }

  const int l = t & 63, wid = t >> 6;
  const int lr = l & 15, lh = l >> 4;
  const int co = bn * 64 + wid * 16 + lr;
  if (co < Cout) {
    const float bvv = bias[co];
#pragma unroll
    for (int m = 0; m < 4; ++m) {
#pragma unroll
      for (int r = 0; r < 4; ++r) {
        const int i = bm * 64 + m * 16 + lh * 4 + r;
        if (i < M) {
          float z = acc[m][r] + bvv;
          if (ACT) z = 1.0f / (1.0f + expf(-z));
          out[(size_t)i * Cout + co] = z;
        }
      }
    }
  }
}

extern "C" void kernel_launch(void* const* d_in, const int* in_sizes, int n_in,
                              void* d_out, int out_size, void* d_ws, size_t ws_size,
                              hipStream_t stream) {
  const float* features = (const float*)d_in[0];
  const int* knn0 = (const int*)d_in[1];
  const int* knn1 = (const int*)d_in[2];
  const int* labels = (const int*)d_in[3];
  const float* kw[5] = {(const float*)d_in[4], (const float*)d_in[6],
                        (const float*)d_in[8], (const float*)d_in[10],
                        (const float*)d_in[12]};
  const float* bw[5] = {(const float*)d_in[5], (const float*)d_in[7],
                        (const float*)d_in[9], (const float*)d_in[11],
                        (const float*)d_in[13]};

  char* ws = (char*)d_ws;
  size_t off = 0;
  auto alloc = [&](size_t bytes) -> void* {
    void* p = ws + off;
    off = (off + bytes + 255) & ~(size_t)255;
    return p;
  };
  unsigned short* Wpk0 = (unsigned short*)alloc((size_t)524288 * 2);
  const int wsz14[4] = {262144, 65536, 16384, 768};
  const int woff14[4] = {0, 262144, 327680, 344064};
  unsigned short* W14 = (unsigned short*)alloc((size_t)344832 * 2);
  int* pool = (int*)alloc((size_t)N1PTS * 256 * 4);
  int* cnt = (int*)alloc((size_t)N1PTS * 4);
  float* pooled = (float*)alloc((size_t)N1PTS * 256 * 4);
  float* f1 = (float*)alloc((size_t)N1PTS * 128 * 4);
  float* f2 = (float*)alloc((size_t)N1PTS * 64 * 4);
  unsigned short* F16 = (unsigned short*)alloc((size_t)NPTS * 256 * 2);
  float* f3 = (float*)pool;  // alias: pool fully consumed (finalize) before layer 3
  if (off > ws_size) return;

  // 1. prepack weights + features (all f16)
  prepack_w0<<<256, 256, 0, stream>>>(kw[0], Wpk0);
  for (int i = 0; i < 4; ++i)
    prepack_w<<<(wsz14[i] + 255) / 256, 256, 0, stream>>>(kw[i + 1], W14 + woff14[i], wsz14[i]);
  prepack_feat<<<(NPTS * 256 / 8 + 255) / 256, 256, 0, stream>>>(features, F16, NPTS * 256 / 8);

  // 2. zero pool+cnt, histogram labels
  hipMemsetAsync(pool, 0, (size_t)N1PTS * 256 * 4 + (size_t)N1PTS * 4, stream);
  count_labels<<<(NPTS + 255) / 256, 256, 0, stream>>>(labels, cnt);

  // 3. layer 0 + fused fixed-point pool scatter
  conv0_gemm<<<1563, 256, 0, stream>>>(F16, knn0, labels, Wpk0, bw[0], pool);

  // 4. pooled mean [N1,256]
  finalize_pool<<<(N1PTS * 256 + 255) / 256, 256, 0, stream>>>(pool, cnt, pooled);

  dim3 blk(256);
  // 5. layer 1: pooled -> f1 [N1,128]
  conv_gemm<true, false><<<dim3(196, 2), blk, 0, stream>>>(
      pooled, knn1, labels, W14 + woff14[0], bw[1], f1, N1PTS, 8, 128, 2048);
  // 6. layer 2: f1 -> f2 [N1,64]
  conv_gemm<true, false><<<dim3(196, 1), blk, 0, stream>>>(
      f1, knn1, labels, W14 + woff14[1], bw[2], f2, N1PTS, 7, 64, 1024);
  // 7. layer 3: gather f2[labels[knn0]] -> f3 [N,32]
  conv_gemm<true, true><<<dim3(1563, 1), blk, 0, stream>>>(
      f2, knn0, labels, W14 + woff14[2], bw[3], f3, NPTS, 6, 32, 512);
  // 8. layer 4: f3 -> out [N,3]
  conv_gemm<false, false><<<dim3(1563, 1), blk, 0, stream>>>(
      f3, knn0, labels, W14 + woff14[3], bw[4], (float*)d_out, NPTS, 5, 3, 256);
}